// Round 7
// baseline (164.850 us; speedup 1.0000x reference)
//
#include <hip/hip_runtime.h>

// ---------------------------------------------------------------------------
// Compile-time Cayley tables for PGA G(3,0,1), basis ordered by grade:
// idx: 0:1 1:e0 2:e1 3:e2 4:e3 5:e01 6:e02 7:e03 8:e12 9:e13 10:e23
//      11:e012 12:e013 13:e023 14:e123 15:e0123
// Blade as 4-bit mask: e0=bit0, e1=bit1, e2=bit2, e3=bit3.
// ---------------------------------------------------------------------------
namespace ga {

constexpr int MASK[16]        = {0,1,2,4,8,3,5,9,6,10,12,7,11,13,14,15};
constexpr int IDX_OF_MASK[16] = {0,1,2,5,3,6,8,11,4,7,9,12,10,13,14,15};

constexpr int popc(int v) { int c = 0; while (v) { c += v & 1; v >>= 1; } return c; }

constexpr int reorder_sign(int a, int b) {
    int s = 0; int t = a >> 1;
    while (t) { s += popc(t & b); t >>= 1; }
    return (s & 1) ? -1 : 1;
}

struct Term { signed char i, j, k, s; };

// Geometric product, metric (0,1,1,1): 192 nonzero terms.
struct GPTab { Term t[192]; };
constexpr GPTab build_gp() {
    GPTab T{}; int n = 0;
    for (int i = 0; i < 16; i++)
        for (int j = 0; j < 16; j++) {
            int a = MASK[i], b = MASK[j];
            if (a & b & 1) continue;                 // e0^2 = 0
            T.t[n].i = (signed char)i;
            T.t[n].j = (signed char)j;
            T.t[n].k = (signed char)IDX_OF_MASK[a ^ b];
            T.t[n].s = (signed char)reorder_sign(a, b);
            n++;
        }
    return T;
}

// Join (sans ref scale): dual(dual(x) ^ dual(y)) folded to 81 terms.
struct JNTab { Term t[81]; };
constexpr JNTab build_join() {
    JNTab T{}; int n = 0;
    int didx[16] = {}, dsgn[16] = {};
    for (int i = 0; i < 16; i++) {
        int a = MASK[i], c = (~a) & 0xF;
        didx[i] = IDX_OF_MASK[c];
        dsgn[i] = reorder_sign(a, c);
    }
    for (int i = 0; i < 16; i++)
        for (int j = 0; j < 16; j++) {
            int p = didx[i], q = didx[j];
            int a = MASK[p], b = MASK[q];
            if (a & b) continue;
            int m = IDX_OF_MASK[a | b];
            int k = didx[m];
            int s = dsgn[i] * dsgn[j] * dsgn[m] * reorder_sign(a, b);
            T.t[n].i = (signed char)i;
            T.t[n].j = (signed char)j;
            T.t[n].k = (signed char)k;
            T.t[n].s = (signed char)s;
            n++;
        }
    return T;
}

constexpr GPTab G = build_gp();
constexpr JNTab J = build_join();

} // namespace ga

// ---------------------------------------------------------------------------
// R14: register-prefetch pipeline + single 8 KB LDS buffer + sustained
// in-flight reads (latency-bound hypothesis test).
//
// Evidence through R13: achieved HBM rate RISES with outstanding traffic
// (117 MB -> 2.4 TB/s; 167 -> 3.0; 292 -> 2.75) — Little's-law signature of
// a latency/concurrency bound, NOT a throughput wall. No variant combined
// sustained per-wave in-flight reads with high residency:
//   R8:  16 w/CU but vmcnt(0) drain every chunk (~50% read duty).
//   R13: counted-vmcnt pipeline but only ~5 w/CU (16 KB LDS left no slack).
//
// R14 structure (1-wave blocks, no barriers):
//   * Pipeline via REGISTER prefetch (float4 P[8], 32 VGPR): cooperative
//     contiguous loads — lane L takes float4 k*64+L -> 1 KB/instruction,
//     copy-identical pattern. No LDS double-buffer needed -> LDS = 8 KB.
//   * Swizzle moves to the ds_write side (per-lane addressing, unlike DMA):
//     float4 g (point p=g>>2, group j=g&3) -> slot (p<<2)|((j+t)&3),
//     t=(p>>1)&3. Same verified conflict-free layout as R11/R13 frag reads.
//   * Steady loop, chunk i: [issue prefetch i+1 (8 loads)] [frags i from
//     LDS] [compute 273 terms] [overlay over consumed buf] [gathers + 8
//     coalesced stores] [vmcnt(8): prefetch landed, stores STILL FLYING]
//     [ds_write P -> buf]. vmcnt never 0 mid-loop. Per wave in flight
//     steadily ~16 KB; 8 blocks/CU -> ~128 KB/CU, ~3x R8 effective.
//   * Grid 2048, NITER=4, gstride=2048: sliding contiguous window (R8's
//     winning order). VGPR live ~118, cap 128 via __launch_bounds__(64,4);
//     spill sentinel: WRITE_SIZE must stay exactly 65536 KB (R9 lesson).
// ---------------------------------------------------------------------------

constexpr int NITER = 4;

__global__ __launch_bounds__(64, 4)
void MVGeometricBilinear_kernel(const float* __restrict__ x,
                                const float* __restrict__ y,
                                const float* __restrict__ ref,
                                float* __restrict__ out,
                                int nchunks, int gstride)
{
    __shared__ __align__(16) float buf[2048];    // x[0..1024) | y[1024..2048)

    const int lane = threadIdx.x;                // block == 1 wave
    const long chunk0 = blockIdx.x;
    if (chunk0 >= nchunks) return;

    // ---- ref prologue: NITER per-lane dword loads (oldest vm ops) ----
    float rr[NITER];
    {
        long c = chunk0;
#pragma unroll
        for (int it = 0; it < NITER; ++it) {
            if (c < nchunks) rr[it] = ref[(c * 64 + lane) * 16 + 15];
            c += gstride;
        }
    }

    // ---- slot maps (R11-verified conflict-free layout) ----
    // write: my prefetch float4 k (g = k*64+lane) -> word addr wslot[k]
    // read:  my point's group k -> word addr fragoff[k] (x; y = +1024)
    int wslot[4], fragoff[4];
#pragma unroll
    for (int k = 0; k < 4; ++k) {
        const int g = k * 64 + lane;
        const int p = g >> 2;
        const int s = (p << 2) | (((g & 3) + ((p >> 1) & 3)) & 3);
        wslot[k] = s << 2;
        fragoff[k] = (lane << 4) + (((k + ((lane >> 1) & 3)) & 3) << 2);
    }

    const float4* gx = reinterpret_cast<const float4*>(x);
    const float4* gy = reinterpret_cast<const float4*>(y);

    float4 P[8];                                 // 32 VGPR prefetch block
    auto prefetch = [&](long c) {                // 8 contiguous 1KB loads
#pragma unroll
        for (int k = 0; k < 4; ++k) P[k]     = gx[c * 256 + k * 64 + lane];
#pragma unroll
        for (int k = 0; k < 4; ++k) P[4 + k] = gy[c * 256 + k * 64 + lane];
    };
    auto commit = [&]() {                        // 8 ds_write_b128, swizzled
#pragma unroll
        for (int k = 0; k < 4; ++k)
            *reinterpret_cast<float4*>(&buf[wslot[k]]) = P[k];
#pragma unroll
        for (int k = 0; k < 4; ++k)
            *reinterpret_cast<float4*>(&buf[1024 + wslot[k]]) = P[4 + k];
    };

    // ---- prologue: chunk0 -> regs -> LDS ----
    prefetch(chunk0);
    asm volatile("s_waitcnt vmcnt(0)" ::: "memory");   // also drains ref loads
    commit();
    asm volatile("" ::: "memory");

    long chunk = chunk0;
#pragma unroll
    for (int it = 0; it < NITER; ++it) {
        const long next = chunk + gstride;
        const bool pf = (it + 1 < NITER) && (next < nchunks);
        if (pf) prefetch(next);                  // P_{i+1} in flight across i

        // ---- fragments: 8 x ds_read_b128, conflict-free ----
        float xx[16], yy[16];
#pragma unroll
        for (int k = 0; k < 4; ++k) {
            const float4 vx = *reinterpret_cast<const float4*>(&buf[fragoff[k]]);
            const float4 vy = *reinterpret_cast<const float4*>(&buf[1024 + fragoff[k]]);
            xx[4*k+0] = vx.x; xx[4*k+1] = vx.y; xx[4*k+2] = vx.z; xx[4*k+3] = vx.w;
            yy[4*k+0] = vy.x; yy[4*k+1] = vy.y; yy[4*k+2] = vy.z; yy[4*k+3] = vy.w;
        }
        const float r = rr[it];

        // ---- compute: full 192 + 81 terms ----
        float gp[16] = {0.f,0.f,0.f,0.f,0.f,0.f,0.f,0.f,
                        0.f,0.f,0.f,0.f,0.f,0.f,0.f,0.f};
        float jn[16] = {0.f,0.f,0.f,0.f,0.f,0.f,0.f,0.f,
                        0.f,0.f,0.f,0.f,0.f,0.f,0.f,0.f};
#pragma unroll
        for (int t = 0; t < 192; t++) {
            const int ti = ga::G.t[t].i, tj = ga::G.t[t].j, tk = ga::G.t[t].k;
            const float v = xx[ti] * yy[tj];
            if (ga::G.t[t].s > 0) gp[tk] += v; else gp[tk] -= v;
        }
#pragma unroll
        for (int t = 0; t < 81; t++) {
            const int ti = ga::J.t[t].i, tj = ga::J.t[t].j, tk = ga::J.t[t].k;
            const float v = xx[ti] * yy[tj];
            if (ga::J.t[t].s > 0) jn[tk] += v; else jn[tk] -= v;
        }

        // Fence: frag reads above, overlay writes below (cross-lane WAR
        // invisible to per-thread alias analysis — R3 lesson).
        asm volatile("" ::: "memory");

        // ---- overlay: stride 32 + XOR(q^(lane&7)) over consumed buffer ----
        const int px = lane & 7;
#pragma unroll
        for (int q = 0; q < 4; q++)
            *reinterpret_cast<float4*>(&buf[lane * 32 + ((q ^ px) << 2)]) =
                make_float4(gp[4*q+0], gp[4*q+1], gp[4*q+2], gp[4*q+3]);
#pragma unroll
        for (int q = 0; q < 4; q++)
            *reinterpret_cast<float4*>(&buf[lane * 32 + (((q + 4) ^ px) << 2)]) =
                make_float4(r*jn[4*q+0], r*jn[4*q+1], r*jn[4*q+2], r*jn[4*q+3]);

        asm volatile("s_waitcnt lgkmcnt(0)" ::: "memory");

        // ---- cooperative full-line stores: 8 x dwordx4/lane (S_i) ----
        {
            float4* go = reinterpret_cast<float4*>(out) + chunk * 512;
#pragma unroll
            for (int c = 0; c < 8; c++) {
                const int g = c * 64 + lane;     // lane-consecutive -> 1 KB/instr
                const int p = g >> 3, q = g & 7;
                go[g] = *reinterpret_cast<const float4*>(
                            &buf[p * 32 + ((q ^ (p & 7)) << 2)]);
            }
        }
        asm volatile("" ::: "memory");

        if (!pf) break;

        // Prefetch landed; stores S_i (8 newer ops) stay in flight.
        asm volatile("s_waitcnt vmcnt(8)" ::: "memory");
        commit();                                // P -> buf for chunk i+1
        asm volatile("" ::: "memory");
        chunk = next;
    }
}

// Tail path (npts not divisible by 64) — scalar per-thread, same math.
__global__ __launch_bounds__(64)
void MVGeometricBilinear_tail(const float* __restrict__ x,
                              const float* __restrict__ y,
                              const float* __restrict__ ref,
                              float* __restrict__ out,
                              int start, int npts)
{
    int pt = start + blockIdx.x * 64 + threadIdx.x;
    if (pt >= npts) return;
    float xx[16], yy[16];
#pragma unroll
    for (int k = 0; k < 16; k++) { xx[k] = x[(size_t)pt*16+k]; yy[k] = y[(size_t)pt*16+k]; }
    const float r = ref[(size_t)pt*16+15];
    float gp[16] = {}, jn[16] = {};
#pragma unroll
    for (int t = 0; t < 192; t++) {
        const float v = xx[ga::G.t[t].i] * yy[ga::G.t[t].j];
        if (ga::G.t[t].s > 0) gp[ga::G.t[t].k] += v; else gp[ga::G.t[t].k] -= v;
    }
#pragma unroll
    for (int t = 0; t < 81; t++) {
        const float v = xx[ga::J.t[t].i] * yy[ga::J.t[t].j];
        if (ga::J.t[t].s > 0) jn[ga::J.t[t].k] += v; else jn[ga::J.t[t].k] -= v;
    }
#pragma unroll
    for (int k = 0; k < 16; k++) out[(size_t)pt*32+k] = gp[k];
#pragma unroll
    for (int k = 0; k < 16; k++) out[(size_t)pt*32+16+k] = r * jn[k];
}

extern "C" void kernel_launch(void* const* d_in, const int* in_sizes, int n_in,
                              void* d_out, int out_size, void* d_ws, size_t ws_size,
                              hipStream_t stream) {
    const float* x   = (const float*)d_in[0];
    const float* y   = (const float*)d_in[1];
    const float* ref = (const float*)d_in[2];
    float* out = (float*)d_out;

    const int npts    = in_sizes[0] / 16;     // B*T = 524288
    const int nchunks = npts / 64;            // 8192

    if (nchunks > 0) {
        // 8 blocks/CU x 256 CU = 2048; each wave walks <= NITER chunks at
        // stride 2048 -> one sliding contiguous address window.
        int blocks = nchunks < 2048 ? nchunks : 2048;
        const int need = (nchunks + NITER - 1) / NITER;
        if (blocks < need) blocks = need;
        MVGeometricBilinear_kernel<<<blocks, 64, 0, stream>>>(
            x, y, ref, out, nchunks, blocks);
    }

    const int rem = npts - nchunks * 64;      // 0 for this shape
    if (rem > 0) {
        MVGeometricBilinear_tail<<<(rem + 63) / 64, 64, 0, stream>>>(
            x, y, ref, out, nchunks * 64, npts);
    }
}